// Round 1
// baseline (9.382 us; speedup 1.0000x reference)
//
#include <hip/hip_runtime.h>
#include <hip/hip_bf16.h>

// FoSae "mask" kernel.
//
// Key insight: PRED_BITS == 1, so the reference's softmax over axis=-1 is a
// softmax over a single element == exactly 1.0, independent of the logits,
// gumbel noise, and temperature. The whole conv/fc encoder is dead code.
// Each of the 3 outputs is a [B, NMAX*NMAX, 1] zeros tensor with 1.0 at
// (tuple_state[t], within_idx[t]) for t in [0, T). All three outputs are
// identical (same tuple indices for every branch).
//
// Single-block kernel: zero-fill out (harness poisons with 0xAA and does not
// re-poison between replays), barrier, then scatter 1.0 into all 3 slabs.

#ifndef NMAX2_P
#define NMAX2_P 64   // NMAX^2 * PRED_BITS = 8*8*1
#endif

__global__ void fosae_mask_kernel(const int* __restrict__ tuple_state,
                                  const int* __restrict__ within_idx,
                                  float* __restrict__ out,
                                  int T, int per_branch) {
    const int tid = threadIdx.x;
    const int nthreads = blockDim.x;
    const int total = 3 * per_branch;

    // Zero-fill the whole output (vector-width is irrelevant at 24 KB).
    for (int i = tid; i < total; i += nthreads) {
        out[i] = 0.0f;
    }
    __syncthreads();

    // Scatter exact 1.0 at each tuple's slot, in each of the 3 output slabs.
    for (int t = tid; t < T; t += nthreads) {
        const int pos = tuple_state[t] * NMAX2_P + within_idx[t];
        out[pos] = 1.0f;
        out[per_branch + pos] = 1.0f;
        out[2 * per_branch + pos] = 1.0f;
    }
}

extern "C" void kernel_launch(void* const* d_in, const int* in_sizes, int n_in,
                              void* d_out, int out_size, void* d_ws, size_t ws_size,
                              hipStream_t stream) {
    // setup_inputs() order:
    //  0 state, 1 state_next, 2 state_tilda,
    //  3 gnoise, 4 gnoise_next, 5 gnoise_tilda,
    //  6 conv_w, 7 conv_b, 8 fc2_w, 9 fc2_b, 10 fc3_w, 11 fc3_b,
    // 12 tuple_state, 13 tuple_a, 14 tuple_b, 15 within_idx, 16 temp
    const int* tuple_state = (const int*)d_in[12];
    const int* within_idx  = (const int*)d_in[15];

    const int T = in_sizes[12];          // == in_sizes[3] since PRED_BITS == 1
    const int per_branch = out_size / 3; // B * NMAX^2 * PRED_BITS = 2048

    fosae_mask_kernel<<<1, 256, 0, stream>>>(tuple_state, within_idx,
                                             (float*)d_out, T, per_branch);
}